// Round 7
// baseline (186.749 us; speedup 1.0000x reference)
//
#include <hip/hip_runtime.h>

#define BATCH 8
#define NN 4096
#define DD 512
#define KK 2048
#define SPLIT 16
#define JSPLIT 8
#define JCH (NN / JSPLIT)             // 512
#define CS_BPB 128                    // colsum blocks per batch
#define CS_ROWS (NN / CS_BPB)         // 32 rows per block
#define ADJ_UNITS (BATCH * KK)                        // 16384
#define H_UNITS (BATCH * KK * (DD / 4) / 256)         // 8192
#define GATHER_GRID 2048

typedef float v4f __attribute__((ext_vector_type(4)));

// ------ col_sum partial: 1024 blocks (4/CU), 2 row-streams, float4 loads -----
__global__ __launch_bounds__(256) void colsum_partial_kernel(
    const float* __restrict__ h, double* __restrict__ partial) {
    int b = blockIdx.x / CS_BPB;
    int c = blockIdx.x % CS_BPB;
    int c4 = threadIdx.x & 127;   // float4 column
    int rr = threadIdx.x >> 7;    // row stream 0..1
    const float4* hp = (const float4*)h +
        ((size_t)(b * NN + c * CS_ROWS)) * (DD / 4) + c4;
    double a0 = 0, a1 = 0, a2 = 0, a3 = 0;
    #pragma unroll
    for (int n = rr; n < CS_ROWS; n += 2) {
        float4 v = hp[(size_t)n * (DD / 4)];
        a0 += v.x; a1 += v.y; a2 += v.z; a3 += v.w;
    }
    // layout: partial[(b*256 + c*2 + rr)*DD + col]
    double* pp = partial + ((size_t)(b * 256 + c * 2 + rr)) * DD + c4 * 4;
    pp[0] = a0; pp[1] = a1; pp[2] = a2; pp[3] = a3;
}

__global__ __launch_bounds__(512) void colsum_reduce_kernel(
    const double* __restrict__ partial, double* __restrict__ colsum) {
    int b = blockIdx.x;
    int d = threadIdx.x;
    double acc = 0.0;
    #pragma unroll 8
    for (int q = 0; q < 256; ++q)
        acc += partial[((size_t)b * 256 + q) * DD + d];
    colsum[b * DD + d] = acc;
}

// ---------------- scores: one wave (64 lanes) per row ------------------------
__global__ __launch_bounds__(256) void scores_kernel(
    const float* __restrict__ h, const double* __restrict__ colsum,
    float* __restrict__ scores) {
    int wave = threadIdx.x >> 6;
    int lane = threadIdx.x & 63;
    int r = blockIdx.x * 4 + wave;            // global row in [0, BATCH*NN)
    int b = r >> 12;                          // r / NN
    const float4* hp = (const float4*)(h + (size_t)r * DD) + lane * 2;
    float4 v0 = hp[0];
    float4 v1 = hp[1];
    const double* cs = colsum + b * DD + lane * 8;
    double acc = (double)v0.x * cs[0] + (double)v0.y * cs[1] +
                 (double)v0.z * cs[2] + (double)v0.w * cs[3] +
                 (double)v1.x * cs[4] + (double)v1.y * cs[5] +
                 (double)v1.z * cs[6] + (double)v1.w * cs[7];
    #pragma unroll
    for (int off = 32; off >= 1; off >>= 1) acc += __shfl_down(acc, off);
    if (lane == 0) scores[r] = (float)acc;
}

// ---------------- partial rank counts: j-range split 8-way, float4 LDS -------
__global__ __launch_bounds__(256) void count_kernel(
    const float* __restrict__ scores, int* __restrict__ pcount) {
    __shared__ float sc[JCH];
    int blk = blockIdx.x;
    int jc = blk % JSPLIT;
    int s  = (blk / JSPLIT) % SPLIT;
    int b  = blk / (JSPLIT * SPLIT);
    const float* srow = scores + b * NN;
    for (int j = threadIdx.x; j < JCH; j += 256) sc[j] = srow[jc * JCH + j];
    __syncthreads();
    int i = s * 256 + threadIdx.x;
    float si = srow[i];
    int jbase = jc * JCH;
    int cnt = 0;
    const float4* sc4 = (const float4*)sc;
    #pragma unroll 4
    for (int jj = 0; jj < JCH / 4; ++jj) {
        float4 sv = sc4[jj];
        int j0 = jbase + jj * 4;
        cnt += (sv.x < si || (sv.x == si && (j0 + 0) < i)) ? 1 : 0;
        cnt += (sv.y < si || (sv.y == si && (j0 + 1) < i)) ? 1 : 0;
        cnt += (sv.z < si || (sv.z == si && (j0 + 2) < i)) ? 1 : 0;
        cnt += (sv.w < si || (sv.w == si && (j0 + 3) < i)) ? 1 : 0;
    }
    pcount[((size_t)jc * BATCH + b) * NN + i] = cnt;
}

// ---------------- compact: combine partial counts -> flags -> index list -----
__global__ __launch_bounds__(1024) void compact_kernel(
    const int* __restrict__ pcount, int* __restrict__ idx) {
    __shared__ int wtot[16];
    int b = blockIdx.x;
    int t = threadIdx.x;
    int lane = t & 63, w = t >> 6;
    int f[4];
    #pragma unroll
    for (int q = 0; q < 4; ++q) {
        int i = t * 4 + q;
        int cnt = 0;
        #pragma unroll
        for (int jc = 0; jc < JSPLIT; ++jc)
            cnt += pcount[((size_t)jc * BATCH + b) * NN + i];
        f[q] = (cnt < KK) ? 1 : 0;
    }
    int local = f[0] + f[1] + f[2] + f[3];
    int scan = local;
    #pragma unroll
    for (int off = 1; off < 64; off <<= 1) {
        int x = __shfl_up(scan, off);
        if (lane >= off) scan += x;
    }
    if (lane == 63) wtot[w] = scan;
    __syncthreads();
    int wbase = 0;
    for (int ww = 0; ww < w; ++ww) wbase += wtot[ww];
    int p = wbase + scan - local;
    int* irow = idx + b * KK;
    #pragma unroll
    for (int q = 0; q < 4; ++q) {
        if (f[q]) irow[p++] = t * 4 + q;
    }
}

// ------- gather: round-4 structure, PLAIN cached loads/stores (no NT) --------
__global__ __launch_bounds__(256) void gather_kernel(
    const float* __restrict__ h, const float* __restrict__ adj,
    const int* __restrict__ idx, float* __restrict__ out_h,
    float* __restrict__ out_adj) {
    for (int u = blockIdx.x; u < ADJ_UNITS + H_UNITS; u += GATHER_GRID) {
        if (u < ADJ_UNITS) {
            int row = u;                        // b*K + k
            int b = row >> 11;
            int src = idx[row];
            const v4f* ap = (const v4f*)adj + ((size_t)b * NN + src) * (NN / 4);
            v4f* op = (v4f*)out_adj + (size_t)row * (NN / 4);
            #pragma unroll
            for (int q = 0; q < 4; ++q) {
                int v = threadIdx.x + q * 256;
                op[v] = ap[v];
            }
        } else {
            int tid = (u - ADJ_UNITS) * 256 + threadIdx.x;  // float4 idx
            int v = tid & 127;
            int row = tid >> 7;
            int b = row >> 11;
            int src = idx[row];
            ((v4f*)out_h)[tid] =
                ((const v4f*)h)[((size_t)b * NN + src) * (DD / 4) + v];
        }
    }
}

extern "C" void kernel_launch(void* const* d_in, const int* in_sizes, int n_in,
                              void* d_out, int out_size, void* d_ws, size_t ws_size,
                              hipStream_t stream) {
    const float* h   = (const float*)d_in[0];
    const float* adj = (const float*)d_in[1];
    float* out = (float*)d_out;
    char* ws = (char*)d_ws;

    double* partial = (double*)ws;                        // 8 MiB (2048 x 512 doubles)
    double* colsum  = (double*)(ws + 8388608);            // 32 KiB
    float*  scores  = (float*)(ws + 8388608 + 32768);     // 128 KiB
    int*    pcount  = (int*)(ws + 8388608 + 32768 + 131072);           // 1 MiB
    int*    idx     = (int*)(ws + 8388608 + 32768 + 131072 + 1048576); // 64 KiB

    hipLaunchKernelGGL(colsum_partial_kernel, dim3(BATCH * CS_BPB), dim3(256), 0, stream, h, partial);
    hipLaunchKernelGGL(colsum_reduce_kernel, dim3(BATCH), dim3(512), 0, stream, partial, colsum);
    hipLaunchKernelGGL(scores_kernel, dim3(BATCH * NN / 4), dim3(256), 0, stream, h, colsum, scores);
    hipLaunchKernelGGL(count_kernel, dim3(BATCH * SPLIT * JSPLIT), dim3(256), 0, stream, scores, pcount);
    hipLaunchKernelGGL(compact_kernel, dim3(BATCH), dim3(1024), 0, stream, pcount, idx);
    hipLaunchKernelGGL(gather_kernel, dim3(GATHER_GRID), dim3(256), 0, stream,
                       h, adj, idx, out, out + (size_t)BATCH * KK * DD);
}

// Round 8
// 168.423 us; speedup vs baseline: 1.1088x; 1.1088x over previous
//
#include <hip/hip_runtime.h>

#define BATCH 8
#define NN 4096
#define DD 512
#define KK 2048
#define SPLIT 16
#define JSPLIT 8
#define JCH (NN / JSPLIT)             // 512
#define CS_BPB 128                    // colsum blocks per batch
#define CS_ROWS (NN / CS_BPB)         // 32 rows per block
#define ADJ_UNITS (BATCH * KK)                        // 16384
#define H_UNITS (BATCH * KK * (DD / 4) / 256)         // 8192
#define GATHER_GRID 2048

typedef float v4f __attribute__((ext_vector_type(4)));

// ------ col_sum partial: 1024 blocks (4/CU), 2 row-streams, float4 loads -----
__global__ __launch_bounds__(256) void colsum_partial_kernel(
    const float* __restrict__ h, double* __restrict__ partial) {
    int b = blockIdx.x / CS_BPB;
    int c = blockIdx.x % CS_BPB;
    int c4 = threadIdx.x & 127;   // float4 column
    int rr = threadIdx.x >> 7;    // row stream 0..1
    const float4* hp = (const float4*)h +
        ((size_t)(b * NN + c * CS_ROWS)) * (DD / 4) + c4;
    double a0 = 0, a1 = 0, a2 = 0, a3 = 0;
    #pragma unroll
    for (int n = rr; n < CS_ROWS; n += 2) {
        float4 v = hp[(size_t)n * (DD / 4)];
        a0 += v.x; a1 += v.y; a2 += v.z; a3 += v.w;
    }
    double* pp = partial + ((size_t)(b * 256 + c * 2 + rr)) * DD + c4 * 4;
    pp[0] = a0; pp[1] = a1; pp[2] = a2; pp[3] = a3;
}

__global__ __launch_bounds__(512) void colsum_reduce_kernel(
    const double* __restrict__ partial, double* __restrict__ colsum) {
    int b = blockIdx.x;
    int d = threadIdx.x;
    double acc = 0.0;
    #pragma unroll 8
    for (int q = 0; q < 256; ++q)
        acc += partial[((size_t)b * 256 + q) * DD + d];
    colsum[b * DD + d] = acc;
}

// ---------------- scores: one wave (64 lanes) per row ------------------------
__global__ __launch_bounds__(256) void scores_kernel(
    const float* __restrict__ h, const double* __restrict__ colsum,
    float* __restrict__ scores) {
    int wave = threadIdx.x >> 6;
    int lane = threadIdx.x & 63;
    int r = blockIdx.x * 4 + wave;            // global row in [0, BATCH*NN)
    int b = r >> 12;                          // r / NN
    const float4* hp = (const float4*)(h + (size_t)r * DD) + lane * 2;
    float4 v0 = hp[0];
    float4 v1 = hp[1];
    const double* cs = colsum + b * DD + lane * 8;
    double acc = (double)v0.x * cs[0] + (double)v0.y * cs[1] +
                 (double)v0.z * cs[2] + (double)v0.w * cs[3] +
                 (double)v1.x * cs[4] + (double)v1.y * cs[5] +
                 (double)v1.z * cs[6] + (double)v1.w * cs[7];
    #pragma unroll
    for (int off = 32; off >= 1; off >>= 1) acc += __shfl_down(acc, off);
    if (lane == 0) scores[r] = (float)acc;
}

// ---------------- partial rank counts: j-range split 8-way, float4 LDS -------
__global__ __launch_bounds__(256) void count_kernel(
    const float* __restrict__ scores, int* __restrict__ pcount) {
    __shared__ float sc[JCH];
    int blk = blockIdx.x;
    int jc = blk % JSPLIT;
    int s  = (blk / JSPLIT) % SPLIT;
    int b  = blk / (JSPLIT * SPLIT);
    const float* srow = scores + b * NN;
    for (int j = threadIdx.x; j < JCH; j += 256) sc[j] = srow[jc * JCH + j];
    __syncthreads();
    int i = s * 256 + threadIdx.x;
    float si = srow[i];
    int jbase = jc * JCH;
    int cnt = 0;
    const float4* sc4 = (const float4*)sc;
    #pragma unroll 4
    for (int jj = 0; jj < JCH / 4; ++jj) {
        float4 sv = sc4[jj];
        int j0 = jbase + jj * 4;
        cnt += (sv.x < si || (sv.x == si && (j0 + 0) < i)) ? 1 : 0;
        cnt += (sv.y < si || (sv.y == si && (j0 + 1) < i)) ? 1 : 0;
        cnt += (sv.z < si || (sv.z == si && (j0 + 2) < i)) ? 1 : 0;
        cnt += (sv.w < si || (sv.w == si && (j0 + 3) < i)) ? 1 : 0;
    }
    pcount[((size_t)jc * BATCH + b) * NN + i] = cnt;
}

// ---------------- compact: combine partial counts -> flags -> index list -----
__global__ __launch_bounds__(1024) void compact_kernel(
    const int* __restrict__ pcount, int* __restrict__ idx) {
    __shared__ int wtot[16];
    int b = blockIdx.x;
    int t = threadIdx.x;
    int lane = t & 63, w = t >> 6;
    int f[4];
    #pragma unroll
    for (int q = 0; q < 4; ++q) {
        int i = t * 4 + q;
        int cnt = 0;
        #pragma unroll
        for (int jc = 0; jc < JSPLIT; ++jc)
            cnt += pcount[((size_t)jc * BATCH + b) * NN + i];
        f[q] = (cnt < KK) ? 1 : 0;
    }
    int local = f[0] + f[1] + f[2] + f[3];
    int scan = local;
    #pragma unroll
    for (int off = 1; off < 64; off <<= 1) {
        int x = __shfl_up(scan, off);
        if (lane >= off) scan += x;
    }
    if (lane == 63) wtot[w] = scan;
    __syncthreads();
    int wbase = 0;
    for (int ww = 0; ww < w; ++ww) wbase += wtot[ww];
    int p = wbase + scan - local;
    int* irow = idx + b * KK;
    #pragma unroll
    for (int q = 0; q < 4; ++q) {
        if (f[q]) irow[p++] = t * 4 + q;
    }
}

// ------- gather: round-4 exact — grid-stride, NT loads (adj) + NT stores -----
__global__ __launch_bounds__(256) void gather_kernel(
    const float* __restrict__ h, const float* __restrict__ adj,
    const int* __restrict__ idx, float* __restrict__ out_h,
    float* __restrict__ out_adj) {
    for (int u = blockIdx.x; u < ADJ_UNITS + H_UNITS; u += GATHER_GRID) {
        if (u < ADJ_UNITS) {
            int row = u;                        // b*K + k
            int b = row >> 11;
            int src = idx[row];
            const v4f* ap = (const v4f*)adj + ((size_t)b * NN + src) * (NN / 4);
            v4f* op = (v4f*)out_adj + (size_t)row * (NN / 4);
            #pragma unroll
            for (int q = 0; q < 4; ++q) {
                int v = threadIdx.x + q * 256;
                v4f val = __builtin_nontemporal_load(ap + v);
                __builtin_nontemporal_store(val, op + v);
            }
        } else {
            int tid = (u - ADJ_UNITS) * 256 + threadIdx.x;  // float4 idx
            int v = tid & 127;
            int row = tid >> 7;
            int b = row >> 11;
            int src = idx[row];
            v4f val = ((const v4f*)h)[((size_t)b * NN + src) * (DD / 4) + v];
            __builtin_nontemporal_store(val, (v4f*)out_h + tid);
        }
    }
}

extern "C" void kernel_launch(void* const* d_in, const int* in_sizes, int n_in,
                              void* d_out, int out_size, void* d_ws, size_t ws_size,
                              hipStream_t stream) {
    const float* h   = (const float*)d_in[0];
    const float* adj = (const float*)d_in[1];
    float* out = (float*)d_out;
    char* ws = (char*)d_ws;

    double* partial = (double*)ws;                        // 8 MiB
    double* colsum  = (double*)(ws + 8388608);            // 32 KiB
    float*  scores  = (float*)(ws + 8388608 + 32768);     // 128 KiB
    int*    pcount  = (int*)(ws + 8388608 + 32768 + 131072);           // 1 MiB
    int*    idx     = (int*)(ws + 8388608 + 32768 + 131072 + 1048576); // 64 KiB

    hipLaunchKernelGGL(colsum_partial_kernel, dim3(BATCH * CS_BPB), dim3(256), 0, stream, h, partial);
    hipLaunchKernelGGL(colsum_reduce_kernel, dim3(BATCH), dim3(512), 0, stream, partial, colsum);
    hipLaunchKernelGGL(scores_kernel, dim3(BATCH * NN / 4), dim3(256), 0, stream, h, colsum, scores);
    hipLaunchKernelGGL(count_kernel, dim3(BATCH * SPLIT * JSPLIT), dim3(256), 0, stream, scores, pcount);
    hipLaunchKernelGGL(compact_kernel, dim3(BATCH), dim3(1024), 0, stream, pcount, idx);
    hipLaunchKernelGGL(gather_kernel, dim3(GATHER_GRID), dim3(256), 0, stream,
                       h, adj, idx, out, out + (size_t)BATCH * KK * DD);
}